// Round 1
// baseline (4594.724 us; speedup 1.0000x reference)
//
#include <hip/hip_runtime.h>
#include <hip/hip_bf16.h>

#define HH 256
#define SS 128
#define BB 8
#define MM 128
#define DD 256
#define TT 256
#define RR 4

__device__ __forceinline__ float bflo(unsigned int u) { return __uint_as_float(u << 16); }
__device__ __forceinline__ float bfhi(unsigned int u) { return __uint_as_float(u & 0xffff0000u); }

// ---------------- f32 -> bf16 (RNE) weight conversion ----------------
__global__ void k_f32_to_bf16(const float* __restrict__ src, unsigned short* __restrict__ dst, int n) {
    int i = blockIdx.x * blockDim.x + threadIdx.x;
    if (i < n) {
        unsigned u = __float_as_uint(src[i]);
        unsigned r = (u + 0x7fffu + ((u >> 16) & 1u)) >> 16;
        dst[i] = (unsigned short)r;
    }
}

// ---------------- X0 = input @ gW_ih0^T + gb_ih0 + gb_hh0 ----------------
__global__ void k_x0(const float* __restrict__ x, const float* __restrict__ Wih0,
                     const float* __restrict__ bih0, const float* __restrict__ bhh0,
                     float* __restrict__ X0) {
    int row = blockIdx.x;
    int i = threadIdx.x;
    const float4* xr = (const float4*)(x + row * DD);
    const float4* wr = (const float4*)(Wih0 + i * DD);
    float a0 = 0.f, a1 = 0.f, a2 = 0.f, a3 = 0.f;
#pragma unroll 8
    for (int k = 0; k < DD / 4; k++) {
        float4 xv = xr[k]; float4 wv = wr[k];
        a0 += xv.x * wv.x; a1 += xv.y * wv.y; a2 += xv.z * wv.z; a3 += xv.w * wv.w;
    }
    X0[row * HH + i] = a0 + a1 + a2 + a3 + bih0[i] + bhh0[i];
}

// ---------------- graph RNN: one WG per batch chain ----------------
__global__ __launch_bounds__(256) void k_graph(
    const float* __restrict__ X0, const int* __restrict__ mask,
    const unsigned short* __restrict__ Whh0, const unsigned short* __restrict__ Wih1,
    const unsigned short* __restrict__ Whh1,
    const float* __restrict__ bih1, const float* __restrict__ bhh1,
    float* __restrict__ GS) {
    __shared__ float h0[HH], h1[HH];
    __shared__ int slen;
    int b = blockIdx.x, i = threadIdx.x;
    if (i == 0) {
        int L = 0;
        for (int t = 0; t < SS; t++) L += mask[b * SS + t];
        slen = L;
    }
    h0[i] = 0.f; h1[i] = 0.f;
    float bias1 = bih1[i] + bhh1[i];
    __syncthreads();
    int len = slen;
    const unsigned short* w0r = Whh0 + i * HH;
    const unsigned short* w1r = Wih1 + i * HH;
    const unsigned short* w2r = Whh1 + i * HH;
    for (int t = 0; t < len; t++) {
        float acc = X0[(b * SS + t) * HH + i];
        for (int k0 = 0; k0 < HH; k0 += 8) {
            uint4 u = *(const uint4*)(w0r + k0);
            float4 hA = *(const float4*)(h0 + k0);
            float4 hB = *(const float4*)(h0 + k0 + 4);
            acc += hA.x * bflo(u.x) + hA.y * bfhi(u.x) + hA.z * bflo(u.y) + hA.w * bfhi(u.y)
                 + hB.x * bflo(u.z) + hB.y * bfhi(u.z) + hB.z * bflo(u.w) + hB.w * bfhi(u.w);
        }
        float nh0 = tanhf(acc);
        __syncthreads();
        h0[i] = nh0;
        __syncthreads();
        float acc1 = bias1;
        for (int k0 = 0; k0 < HH; k0 += 8) {
            uint4 u1 = *(const uint4*)(w1r + k0);
            uint4 u2 = *(const uint4*)(w2r + k0);
            float4 hA = *(const float4*)(h0 + k0);
            float4 hB = *(const float4*)(h0 + k0 + 4);
            float4 gA = *(const float4*)(h1 + k0);
            float4 gB = *(const float4*)(h1 + k0 + 4);
            acc1 += hA.x * bflo(u1.x) + hA.y * bfhi(u1.x) + hA.z * bflo(u1.y) + hA.w * bfhi(u1.y)
                  + hB.x * bflo(u1.z) + hB.y * bfhi(u1.z) + hB.z * bflo(u1.w) + hB.w * bfhi(u1.w)
                  + gA.x * bflo(u2.x) + gA.y * bfhi(u2.x) + gA.z * bflo(u2.y) + gA.w * bfhi(u2.y)
                  + gB.x * bflo(u2.z) + gB.y * bfhi(u2.z) + gB.z * bflo(u2.w) + gB.w * bfhi(u2.w);
        }
        float nh1 = tanhf(acc1);
        __syncthreads();
        h1[i] = nh1;
        GS[(b * SS + t) * HH + i] = nh1;
        __syncthreads();
    }
    for (int t = len; t < SS; t++) GS[(b * SS + t) * HH + i] = 0.f;
}

// ---------------- edge RNN scan: R=4 rows per WG, no grid sync ----------------
__global__ __launch_bounds__(256) void k_edge(
    const float* __restrict__ GS,
    const unsigned short* __restrict__ Whh0, const unsigned short* __restrict__ Wih1,
    const unsigned short* __restrict__ Whh1,
    const float* __restrict__ Wih0f,  // eW_ih0 in f32 (256 x 128), used column-wise
    const float* __restrict__ bih0, const float* __restrict__ bhh0,
    const float* __restrict__ bih1, const float* __restrict__ bhh1,
    const float* __restrict__ clsW, const float* __restrict__ clsB,
    float* __restrict__ arc) {
    __shared__ float h0b[2][RR][HH];
    __shared__ float h1b[2][RR][HH];
    __shared__ float xw0[RR][HH];
    __shared__ float red[RR][4];
    __shared__ float edge_s[RR];
    int i = threadIdx.x;
    int r0 = blockIdx.x * RR;
    for (int r = 0; r < RR; r++) {
        float g = GS[(r0 + r) * HH + i];
        h0b[0][r][i] = g;
        h1b[0][r][i] = g;
        xw0[r][i] = bih0[i] + bhh0[i];
    }
    float bias1 = bih1[i] + bhh1[i];
    float clsw = clsW[i];
    float clsb = clsB[0];
    const unsigned short* w0r = Whh0 + i * HH;
    const unsigned short* w1r = Wih1 + i * HH;
    const unsigned short* w2r = Whh1 + i * HH;
    int lane = i & 63, wid = i >> 6;
    __syncthreads();
    for (int j = 0; j < MM; j++) {
        int jr = j & 1, jw = jr ^ 1;
        // ---- layer 0: pre0 = xw0 + h0 @ Whh0^T ; e0 = tanh ----
        float acc[RR];
#pragma unroll
        for (int r = 0; r < RR; r++) acc[r] = xw0[r][i];
        for (int k0 = 0; k0 < HH; k0 += 8) {
            uint4 u = *(const uint4*)(w0r + k0);
            float w0 = bflo(u.x), w1 = bfhi(u.x), w2 = bflo(u.y), w3 = bfhi(u.y),
                  w4 = bflo(u.z), w5 = bfhi(u.z), w6 = bflo(u.w), w7 = bfhi(u.w);
#pragma unroll
            for (int r = 0; r < RR; r++) {
                float4 hA = *(const float4*)(&h0b[jr][r][k0]);
                float4 hB = *(const float4*)(&h0b[jr][r][k0 + 4]);
                acc[r] += hA.x * w0 + hA.y * w1 + hA.z * w2 + hA.w * w3
                        + hB.x * w4 + hB.y * w5 + hB.z * w6 + hB.w * w7;
            }
        }
#pragma unroll
        for (int r = 0; r < RR; r++) h0b[jw][r][i] = tanhf(acc[r]);
        __syncthreads();
        // ---- layer 1: pre1 = e0 @ Wih1^T + h1 @ Whh1^T + bias ; e1 = tanh ----
        float acc1[RR];
#pragma unroll
        for (int r = 0; r < RR; r++) acc1[r] = bias1;
        for (int k0 = 0; k0 < HH; k0 += 8) {
            uint4 u1 = *(const uint4*)(w1r + k0);
            uint4 u2 = *(const uint4*)(w2r + k0);
            float a0 = bflo(u1.x), a1 = bfhi(u1.x), a2 = bflo(u1.y), a3 = bfhi(u1.y),
                  a4 = bflo(u1.z), a5 = bfhi(u1.z), a6 = bflo(u1.w), a7 = bfhi(u1.w);
            float c0 = bflo(u2.x), c1 = bfhi(u2.x), c2 = bflo(u2.y), c3 = bfhi(u2.y),
                  c4 = bflo(u2.z), c5 = bfhi(u2.z), c6 = bflo(u2.w), c7 = bfhi(u2.w);
#pragma unroll
            for (int r = 0; r < RR; r++) {
                float4 eA = *(const float4*)(&h0b[jw][r][k0]);
                float4 eB = *(const float4*)(&h0b[jw][r][k0 + 4]);
                float4 gA = *(const float4*)(&h1b[jr][r][k0]);
                float4 gB = *(const float4*)(&h1b[jr][r][k0 + 4]);
                acc1[r] += eA.x * a0 + eA.y * a1 + eA.z * a2 + eA.w * a3
                         + eB.x * a4 + eB.y * a5 + eB.z * a6 + eB.w * a7
                         + gA.x * c0 + gA.y * c1 + gA.z * c2 + gA.w * c3
                         + gB.x * c4 + gB.y * c5 + gB.z * c6 + gB.w * c7;
            }
        }
        float part[RR];
#pragma unroll
        for (int r = 0; r < RR; r++) {
            float e1 = tanhf(acc1[r]);
            h1b[jw][r][i] = e1;
            part[r] = clsw * e1;
        }
        // ---- cls dot: wave shuffle reduce, then cross-wave via LDS ----
#pragma unroll
        for (int r = 0; r < RR; r++) {
            for (int off = 32; off; off >>= 1) part[r] += __shfl_xor(part[r], off);
        }
        if (lane == 0) {
#pragma unroll
            for (int r = 0; r < RR; r++) red[r][wid] = part[r];
        }
        __syncthreads();
        if (i < RR) {
            float s = red[i][0] + red[i][1] + red[i][2] + red[i][3] + clsb;
            edge_s[i] = 1.f / (1.f + expf(-s));
        }
        __syncthreads();
        // ---- rank-1 update of xw0; store arc with strict-lower mask ----
        float wcol = Wih0f[i * MM + j];
#pragma unroll
        for (int r = 0; r < RR; r++) xw0[r][i] += edge_s[r] * wcol;
        if (i < RR) {
            int row = r0 + i;
            int b = row >> 7, s = row & 127;
            arc[b * (MM * SS) + j * SS + s] = (j < s) ? edge_s[i] : 0.f;
        }
        __syncthreads();
    }
}

// ---------------- head/dep tags: elu(GS @ W^T + b) ----------------
__global__ void k_heads(const float* __restrict__ GS,
                        const float* __restrict__ W, const float* __restrict__ bias,
                        float* __restrict__ out) {
    int row = blockIdx.x;
    int i = threadIdx.x;
    const float4* gr = (const float4*)(GS + row * HH);
    const float4* wr = (const float4*)(W + i * HH);
    float a0 = 0.f, a1 = 0.f, a2 = 0.f, a3 = 0.f;
#pragma unroll 8
    for (int k = 0; k < HH / 4; k++) {
        float4 g = gr[k]; float4 w = wr[k];
        a0 += g.x * w.x; a1 += g.y * w.y; a2 += g.z * w.z; a3 += g.w * w.w;
    }
    float v = a0 + a1 + a2 + a3 + bias[i];
    out[row * TT + i] = (v > 0.f) ? v : expm1f(v);
}

extern "C" void kernel_launch(void* const* d_in, const int* in_sizes, int n_in,
                              void* d_out, int out_size, void* d_ws, size_t ws_size,
                              hipStream_t stream) {
    const float* input  = (const float*)d_in[0];
    const int*   mask   = (const int*)d_in[2];
    const float* gW_ih0 = (const float*)d_in[5];
    const float* gW_hh0 = (const float*)d_in[6];
    const float* gb_ih0 = (const float*)d_in[7];
    const float* gb_hh0 = (const float*)d_in[8];
    const float* gW_ih1 = (const float*)d_in[9];
    const float* gW_hh1 = (const float*)d_in[10];
    const float* gb_ih1 = (const float*)d_in[11];
    const float* gb_hh1 = (const float*)d_in[12];
    const float* eW_ih0 = (const float*)d_in[13];
    const float* eW_hh0 = (const float*)d_in[14];
    const float* eb_ih0 = (const float*)d_in[15];
    const float* eb_hh0 = (const float*)d_in[16];
    const float* eW_ih1 = (const float*)d_in[17];
    const float* eW_hh1 = (const float*)d_in[18];
    const float* eb_ih1 = (const float*)d_in[19];
    const float* eb_hh1 = (const float*)d_in[20];
    const float* cls_W  = (const float*)d_in[21];
    const float* cls_b  = (const float*)d_in[22];
    const float* head_W = (const float*)d_in[23];
    const float* head_b = (const float*)d_in[24];
    const float* dep_W  = (const float*)d_in[25];
    const float* dep_b  = (const float*)d_in[26];

    float* out      = (float*)d_out;
    float* head_out = out;                 // 8*128*256 = 262144
    float* dep_out  = out + 262144;        // 262144
    float* arc_out  = out + 524288;        // 8*128*128 = 131072

    char* ws = (char*)d_ws;
    float* X0 = (float*)ws;                         // 1 MB
    float* GS = (float*)(ws + (1 << 20));           // 1 MB
    unsigned short* wb = (unsigned short*)(ws + (2 << 20));  // 6 x 65536 bf16
    unsigned short* bg_hh0 = wb;
    unsigned short* bg_ih1 = wb + 65536;
    unsigned short* bg_hh1 = wb + 2 * 65536;
    unsigned short* be_hh0 = wb + 3 * 65536;
    unsigned short* be_ih1 = wb + 4 * 65536;
    unsigned short* be_hh1 = wb + 5 * 65536;

    k_f32_to_bf16<<<256, 256, 0, stream>>>(gW_hh0, bg_hh0, 65536);
    k_f32_to_bf16<<<256, 256, 0, stream>>>(gW_ih1, bg_ih1, 65536);
    k_f32_to_bf16<<<256, 256, 0, stream>>>(gW_hh1, bg_hh1, 65536);
    k_f32_to_bf16<<<256, 256, 0, stream>>>(eW_hh0, be_hh0, 65536);
    k_f32_to_bf16<<<256, 256, 0, stream>>>(eW_ih1, be_ih1, 65536);
    k_f32_to_bf16<<<256, 256, 0, stream>>>(eW_hh1, be_hh1, 65536);

    k_x0<<<1024, 256, 0, stream>>>(input, gW_ih0, gb_ih0, gb_hh0, X0);
    k_graph<<<8, 256, 0, stream>>>(X0, mask, bg_hh0, bg_ih1, bg_hh1, gb_ih1, gb_hh1, GS);
    k_edge<<<256, 256, 0, stream>>>(GS, be_hh0, be_ih1, be_hh1, eW_ih0,
                                    eb_ih0, eb_hh0, eb_ih1, eb_hh1, cls_W, cls_b, arc_out);
    k_heads<<<1024, 256, 0, stream>>>(GS, head_W, head_b, head_out);
    k_heads<<<1024, 256, 0, stream>>>(GS, dep_W, dep_b, dep_out);
}

// Round 2
// 1811.586 us; speedup vs baseline: 2.5363x; 2.5363x over previous
//
#include <hip/hip_runtime.h>
#include <hip/hip_bf16.h>

#define HH 256
#define SS 128
#define BB 8
#define MM 128
#define DD 256
#define TT 256
#define GG 16   // rows per edge WG
#define NW 8    // waves per edge WG

typedef float  f32x4  __attribute__((ext_vector_type(4)));
typedef short  bf16x8 __attribute__((ext_vector_type(8)));

__device__ __forceinline__ float bflo(unsigned int u) { return __uint_as_float(u << 16); }
__device__ __forceinline__ float bfhi(unsigned int u) { return __uint_as_float(u & 0xffff0000u); }
__device__ __forceinline__ unsigned short f2bf(float x) {
    unsigned u = __float_as_uint(x);
    return (unsigned short)((u + 0x7fffu + ((u >> 16) & 1u)) >> 16);
}

// ---------------- f32 -> bf16 (RNE) flat conversion (graph weights) ----------------
__global__ void k_f32_to_bf16(const float* __restrict__ src, unsigned short* __restrict__ dst, int n) {
    int i = blockIdx.x * blockDim.x + threadIdx.x;
    if (i < n) dst[i] = f2bf(src[i]);
}

// ---------------- pack 256x256 W (row-major, out x in) into MFMA A-fragments ----------------
// frag f = ct*8 + kb  (ct: 16 col-tiles of output neurons, kb: 8 k-blocks of 32)
// lane l holds W[ct*16 + (l&15)][kb*32 + (l>>4)*4 + (e&3) + 16*(e>>2)], e = 0..7
// stored contiguously: pk[(f*64 + l)*8 + e]
__global__ void k_pack(const float* __restrict__ W, unsigned short* __restrict__ pk) {
    int idx = blockIdx.x * 256 + threadIdx.x;   // 8192 = 128 frags * 64 lanes
    int f = idx >> 6, l = idx & 63;
    int ct = f >> 3, kb = f & 7, q = l >> 4, m = l & 15;
    unsigned short out[8];
#pragma unroll
    for (int e = 0; e < 8; e++) {
        int k = kb * 32 + q * 4 + (e & 3) + ((e >> 2) << 4);
        out[e] = f2bf(W[(ct * 16 + m) * HH + k]);
    }
    uint4 v;
    v.x = out[0] | ((unsigned)out[1] << 16);
    v.y = out[2] | ((unsigned)out[3] << 16);
    v.z = out[4] | ((unsigned)out[5] << 16);
    v.w = out[6] | ((unsigned)out[7] << 16);
    *(uint4*)(pk + idx * 8) = v;
}

// ---------------- transpose eW_ih0 (256 x 128) -> (128 x 256) f32 ----------------
__global__ void k_transp(const float* __restrict__ in, float* __restrict__ out) {
    int idx = blockIdx.x * 256 + threadIdx.x;   // 32768
    int j = idx >> 8, c = idx & 255;
    out[idx] = in[c * MM + j];
}

// ---------------- X0 = input @ gW_ih0^T + gb_ih0 + gb_hh0 ----------------
__global__ void k_x0(const float* __restrict__ x, const float* __restrict__ Wih0,
                     const float* __restrict__ bih0, const float* __restrict__ bhh0,
                     float* __restrict__ X0) {
    int row = blockIdx.x;
    int i = threadIdx.x;
    const float4* xr = (const float4*)(x + row * DD);
    const float4* wr = (const float4*)(Wih0 + i * DD);
    float a0 = 0.f, a1 = 0.f, a2 = 0.f, a3 = 0.f;
#pragma unroll 8
    for (int k = 0; k < DD / 4; k++) {
        float4 xv = xr[k]; float4 wv = wr[k];
        a0 += xv.x * wv.x; a1 += xv.y * wv.y; a2 += xv.z * wv.z; a3 += xv.w * wv.w;
    }
    X0[row * HH + i] = a0 + a1 + a2 + a3 + bih0[i] + bhh0[i];
}

// ---------------- graph RNN: one WG per batch chain (unchanged from R1) ----------------
__global__ __launch_bounds__(256) void k_graph(
    const float* __restrict__ X0, const int* __restrict__ mask,
    const unsigned short* __restrict__ Whh0, const unsigned short* __restrict__ Wih1,
    const unsigned short* __restrict__ Whh1,
    const float* __restrict__ bih1, const float* __restrict__ bhh1,
    float* __restrict__ GS) {
    __shared__ float h0[HH], h1[HH];
    __shared__ int slen;
    int b = blockIdx.x, i = threadIdx.x;
    if (i == 0) {
        int L = 0;
        for (int t = 0; t < SS; t++) L += mask[b * SS + t];
        slen = L;
    }
    h0[i] = 0.f; h1[i] = 0.f;
    float bias1 = bih1[i] + bhh1[i];
    __syncthreads();
    int len = slen;
    const unsigned short* w0r = Whh0 + i * HH;
    const unsigned short* w1r = Wih1 + i * HH;
    const unsigned short* w2r = Whh1 + i * HH;
    for (int t = 0; t < len; t++) {
        float acc = X0[(b * SS + t) * HH + i];
        for (int k0 = 0; k0 < HH; k0 += 8) {
            uint4 u = *(const uint4*)(w0r + k0);
            float4 hA = *(const float4*)(h0 + k0);
            float4 hB = *(const float4*)(h0 + k0 + 4);
            acc += hA.x * bflo(u.x) + hA.y * bfhi(u.x) + hA.z * bflo(u.y) + hA.w * bfhi(u.y)
                 + hB.x * bflo(u.z) + hB.y * bfhi(u.z) + hB.z * bflo(u.w) + hB.w * bfhi(u.w);
        }
        float nh0 = tanhf(acc);
        __syncthreads();
        h0[i] = nh0;
        __syncthreads();
        float acc1 = bias1;
        for (int k0 = 0; k0 < HH; k0 += 8) {
            uint4 u1 = *(const uint4*)(w1r + k0);
            uint4 u2 = *(const uint4*)(w2r + k0);
            float4 hA = *(const float4*)(h0 + k0);
            float4 hB = *(const float4*)(h0 + k0 + 4);
            float4 gA = *(const float4*)(h1 + k0);
            float4 gB = *(const float4*)(h1 + k0 + 4);
            acc1 += hA.x * bflo(u1.x) + hA.y * bfhi(u1.x) + hA.z * bflo(u1.y) + hA.w * bfhi(u1.y)
                  + hB.x * bflo(u1.z) + hB.y * bfhi(u1.z) + hB.z * bflo(u1.w) + hB.w * bfhi(u1.w)
                  + gA.x * bflo(u2.x) + gA.y * bfhi(u2.x) + gA.z * bflo(u2.y) + gA.w * bfhi(u2.y)
                  + gB.x * bflo(u2.z) + gB.y * bfhi(u2.z) + gB.z * bflo(u2.w) + gB.w * bfhi(u2.w);
        }
        float nh1 = tanhf(acc1);
        __syncthreads();
        h1[i] = nh1;
        GS[(b * SS + t) * HH + i] = nh1;
        __syncthreads();
    }
    for (int t = len; t < SS; t++) GS[(b * SS + t) * HH + i] = 0.f;
}

// ---------------- edge RNN scan, MFMA version ----------------
// 64 WGs x 512 threads. Each WG owns GG=16 rows; 8 waves, wave w owns output
// col-tiles {2w, 2w+1}. Swapped operands: D[m=outneuron][n=datarow], so
// lane l holds rows r=l&15, out-cols c = ct*16 + (l>>4)*4 + reg  (m89 layout).
__device__ __forceinline__ bf16x8 ldA(const unsigned short* __restrict__ pk, int ct, int kb, int lane) {
    return *(const bf16x8*)(pk + (((ct * 8 + kb) * 64 + lane) << 3));
}
__device__ __forceinline__ bf16x8 ldB(const unsigned short* h, int kb, int q) {
    // h points at row base h[r][0]; k = kb*32 + q*4 + (e&3) + 16*(e>>2)
    const unsigned short* p = h + kb * 32 + q * 4;
    ushort4 lo = *(const ushort4*)p;
    ushort4 hi = *(const ushort4*)(p + 16);
    bf16x8 f;
    f[0] = lo.x; f[1] = lo.y; f[2] = lo.z; f[3] = lo.w;
    f[4] = hi.x; f[5] = hi.y; f[6] = hi.z; f[7] = hi.w;
    return f;
}

__global__ __launch_bounds__(512) void k_edge_mfma(
    const float* __restrict__ GS,
    const unsigned short* __restrict__ pk0,  // eW_hh0 packed
    const unsigned short* __restrict__ pk1,  // eW_ih1 packed
    const unsigned short* __restrict__ pk2,  // eW_hh1 packed
    const float* __restrict__ eWT,           // eW_ih0^T (128 x 256) f32
    const float* __restrict__ bih0, const float* __restrict__ bhh0,
    const float* __restrict__ bih1, const float* __restrict__ bhh1,
    const float* __restrict__ clsW, const float* __restrict__ clsB,
    float* __restrict__ arc) {
    __shared__ unsigned short h0[2][GG][264];
    __shared__ unsigned short h1[2][GG][264];
    __shared__ float xw0[GG][260];
    __shared__ float red[NW][GG];
    __shared__ float edge_s[GG];

    int tid = threadIdx.x;
    int wv = tid >> 6, lane = tid & 63;
    int q = lane >> 4, rr = lane & 15;
    int ct0 = 2 * wv, ct1 = 2 * wv + 1;
    int r0 = blockIdx.x * GG;

    // ---- init: h0 = h1 = bf16(GS rows); xw0 = bih0 + bhh0 ----
    {
        int r = tid >> 5, c0 = (tid & 31) * 8;
        const float* g = GS + (r0 + r) * HH + c0;
        unsigned short t8[8];
#pragma unroll
        for (int e = 0; e < 8; e++) {
            float v = g[e];
            t8[e] = f2bf(v);
            xw0[r][c0 + e] = bih0[c0 + e] + bhh0[c0 + e];
        }
        uint4 pv;
        pv.x = t8[0] | ((unsigned)t8[1] << 16);
        pv.y = t8[2] | ((unsigned)t8[3] << 16);
        pv.z = t8[4] | ((unsigned)t8[5] << 16);
        pv.w = t8[6] | ((unsigned)t8[7] << 16);
        *(uint4*)&h0[0][r][c0] = pv;
        *(uint4*)&h1[0][r][c0] = pv;
    }
    // per-lane constants: bias1 and clsW for owned out-cols
    float b1a[4], b1b[4], cwa[4], cwb[4];
#pragma unroll
    for (int reg = 0; reg < 4; reg++) {
        int cA = ct0 * 16 + q * 4 + reg;
        int cB = ct1 * 16 + q * 4 + reg;
        b1a[reg] = bih1[cA] + bhh1[cA];
        b1b[reg] = bih1[cB] + bhh1[cB];
        cwa[reg] = clsW[cA];
        cwb[reg] = clsW[cB];
    }
    float clsb = clsB[0];
    __syncthreads();

    for (int j = 0; j < MM; j++) {
        int jr = j & 1, jw = jr ^ 1;
        // ---- S1: pre0 = xw0 + h0 @ Whh0^T  (acc in D layout) ----
        f32x4 acc0 = *(const f32x4*)&xw0[rr][ct0 * 16 + q * 4];
        f32x4 acc1 = *(const f32x4*)&xw0[rr][ct1 * 16 + q * 4];
#pragma unroll
        for (int kb = 0; kb < 8; kb++) {
            bf16x8 b = ldB(&h0[jr][rr][0], kb, q);
            acc0 = __builtin_amdgcn_mfma_f32_16x16x32_bf16(ldA(pk0, ct0, kb, lane), b, acc0, 0, 0, 0);
            acc1 = __builtin_amdgcn_mfma_f32_16x16x32_bf16(ldA(pk0, ct1, kb, lane), b, acc1, 0, 0, 0);
        }
        // e0 = tanh; write to h0[jw] (dbuf -> no read/write hazard)
        unsigned short e0a[4], e0b[4];
#pragma unroll
        for (int reg = 0; reg < 4; reg++) {
            e0a[reg] = f2bf(tanhf(acc0[reg]));
            e0b[reg] = f2bf(tanhf(acc1[reg]));
        }
        {
            ushort4 pa = { e0a[0], e0a[1], e0a[2], e0a[3] };
            ushort4 pb = { e0b[0], e0b[1], e0b[2], e0b[3] };
            *(ushort4*)&h0[jw][rr][ct0 * 16 + q * 4] = pa;
            *(ushort4*)&h0[jw][rr][ct1 * 16 + q * 4] = pb;
        }
        __syncthreads();   // B1: h0[jw] visible
        // ---- S3: pre1 = e0 @ Wih1^T + h1 @ Whh1^T + bias1 ----
        f32x4 p0 = { b1a[0], b1a[1], b1a[2], b1a[3] };
        f32x4 p1 = { b1b[0], b1b[1], b1b[2], b1b[3] };
#pragma unroll
        for (int kb = 0; kb < 8; kb++) {
            bf16x8 be = ldB(&h0[jw][rr][0], kb, q);
            bf16x8 bh = ldB(&h1[jr][rr][0], kb, q);
            p0 = __builtin_amdgcn_mfma_f32_16x16x32_bf16(ldA(pk1, ct0, kb, lane), be, p0, 0, 0, 0);
            p1 = __builtin_amdgcn_mfma_f32_16x16x32_bf16(ldA(pk1, ct1, kb, lane), be, p1, 0, 0, 0);
            p0 = __builtin_amdgcn_mfma_f32_16x16x32_bf16(ldA(pk2, ct0, kb, lane), bh, p0, 0, 0, 0);
            p1 = __builtin_amdgcn_mfma_f32_16x16x32_bf16(ldA(pk2, ct1, kb, lane), bh, p1, 0, 0, 0);
        }
        float e1a[4], e1b[4];
        float part = 0.f;
#pragma unroll
        for (int reg = 0; reg < 4; reg++) {
            e1a[reg] = tanhf(p0[reg]);
            e1b[reg] = tanhf(p1[reg]);
            part += cwa[reg] * e1a[reg] + cwb[reg] * e1b[reg];
        }
        // reduce over q (lanes ^16, ^32): per-row cls partial within wave
        part += __shfl_xor(part, 16);
        part += __shfl_xor(part, 32);
        if (lane < 16) red[wv][lane] = part;
        __syncthreads();   // B2: red visible; everyone done reading h1[jr]
        // ---- S4: h1[jw] write + edge sigmoid ----
        {
            ushort4 pa = { f2bf(e1a[0]), f2bf(e1a[1]), f2bf(e1a[2]), f2bf(e1a[3]) };
            ushort4 pb = { f2bf(e1b[0]), f2bf(e1b[1]), f2bf(e1b[2]), f2bf(e1b[3]) };
            *(ushort4*)&h1[jw][rr][ct0 * 16 + q * 4] = pa;
            *(ushort4*)&h1[jw][rr][ct1 * 16 + q * 4] = pb;
        }
        if (tid < GG) {
            float s = clsb;
#pragma unroll
            for (int w = 0; w < NW; w++) s += red[w][tid];
            edge_s[tid] = 1.f / (1.f + expf(-s));
        }
        __syncthreads();   // B3: edge_s visible
        // ---- S5: xw0 += edge (x) eW_ih0[:,j] ; arc store ----
        {
            int r = tid >> 5, c0 = (tid & 31) * 8;
            float e = edge_s[r];
            const float* wj = eWT + j * HH + c0;
#pragma unroll
            for (int k = 0; k < 8; k++) xw0[r][c0 + k] += e * wj[k];
        }
        if (tid < GG) {
            int row = r0 + tid;
            int b = row >> 7, s = row & 127;
            arc[b * (MM * SS) + j * SS + s] = (j < s) ? edge_s[tid] : 0.f;
        }
        __syncthreads();   // B4: xw0 stable for next step
    }
}

// ---------------- head/dep tags: elu(GS @ W^T + b) ----------------
__global__ void k_heads(const float* __restrict__ GS,
                        const float* __restrict__ W, const float* __restrict__ bias,
                        float* __restrict__ out) {
    int row = blockIdx.x;
    int i = threadIdx.x;
    const float4* gr = (const float4*)(GS + row * HH);
    const float4* wr = (const float4*)(W + i * HH);
    float a0 = 0.f, a1 = 0.f, a2 = 0.f, a3 = 0.f;
#pragma unroll 8
    for (int k = 0; k < HH / 4; k++) {
        float4 g = gr[k]; float4 w = wr[k];
        a0 += g.x * w.x; a1 += g.y * w.y; a2 += g.z * w.z; a3 += g.w * w.w;
    }
    float v = a0 + a1 + a2 + a3 + bias[i];
    out[row * TT + i] = (v > 0.f) ? v : expm1f(v);
}

extern "C" void kernel_launch(void* const* d_in, const int* in_sizes, int n_in,
                              void* d_out, int out_size, void* d_ws, size_t ws_size,
                              hipStream_t stream) {
    const float* input  = (const float*)d_in[0];
    const int*   mask   = (const int*)d_in[2];
    const float* gW_ih0 = (const float*)d_in[5];
    const float* gW_hh0 = (const float*)d_in[6];
    const float* gb_ih0 = (const float*)d_in[7];
    const float* gb_hh0 = (const float*)d_in[8];
    const float* gW_ih1 = (const float*)d_in[9];
    const float* gW_hh1 = (const float*)d_in[10];
    const float* gb_ih1 = (const float*)d_in[11];
    const float* gb_hh1 = (const float*)d_in[12];
    const float* eW_ih0 = (const float*)d_in[13];
    const float* eW_hh0 = (const float*)d_in[14];
    const float* eb_ih0 = (const float*)d_in[15];
    const float* eb_hh0 = (const float*)d_in[16];
    const float* eW_ih1 = (const float*)d_in[17];
    const float* eW_hh1 = (const float*)d_in[18];
    const float* eb_ih1 = (const float*)d_in[19];
    const float* eb_hh1 = (const float*)d_in[20];
    const float* cls_W  = (const float*)d_in[21];
    const float* cls_b  = (const float*)d_in[22];
    const float* head_W = (const float*)d_in[23];
    const float* head_b = (const float*)d_in[24];
    const float* dep_W  = (const float*)d_in[25];
    const float* dep_b  = (const float*)d_in[26];

    float* out      = (float*)d_out;
    float* head_out = out;                 // 8*128*256
    float* dep_out  = out + 262144;
    float* arc_out  = out + 524288;        // 8*128*128

    char* ws = (char*)d_ws;
    float* X0 = (float*)ws;                                  // 1 MB
    float* GS = (float*)(ws + (1 << 20));                    // 1 MB
    unsigned short* bg_hh0 = (unsigned short*)(ws + (2 << 20));            // 128 KB each
    unsigned short* bg_ih1 = bg_hh0 + 65536;
    unsigned short* bg_hh1 = bg_hh0 + 2 * 65536;
    unsigned short* pk_ehh0 = bg_hh0 + 3 * 65536;
    unsigned short* pk_eih1 = bg_hh0 + 4 * 65536;
    unsigned short* pk_ehh1 = bg_hh0 + 5 * 65536;
    float* eWT = (float*)(bg_hh0 + 6 * 65536);               // 128 KB

    // graph-side bf16 weights (scalar-decode path)
    k_f32_to_bf16<<<256, 256, 0, stream>>>(gW_hh0, bg_hh0, 65536);
    k_f32_to_bf16<<<256, 256, 0, stream>>>(gW_ih1, bg_ih1, 65536);
    k_f32_to_bf16<<<256, 256, 0, stream>>>(gW_hh1, bg_hh1, 65536);
    // edge-side MFMA fragment packing + eW_ih0 transpose
    k_pack<<<32, 256, 0, stream>>>(eW_hh0, pk_ehh0);
    k_pack<<<32, 256, 0, stream>>>(eW_ih1, pk_eih1);
    k_pack<<<32, 256, 0, stream>>>(eW_hh1, pk_ehh1);
    k_transp<<<128, 256, 0, stream>>>(eW_ih0, eWT);

    k_x0<<<1024, 256, 0, stream>>>(input, gW_ih0, gb_ih0, gb_hh0, X0);
    k_graph<<<8, 256, 0, stream>>>(X0, mask, bg_hh0, bg_ih1, bg_hh1, gb_ih1, gb_hh1, GS);
    k_edge_mfma<<<64, 512, 0, stream>>>(GS, pk_ehh0, pk_eih1, pk_ehh1, eWT,
                                        eb_ih0, eb_hh0, eb_ih1, eb_hh1, cls_W, cls_b, arc_out);
    k_heads<<<1024, 256, 0, stream>>>(GS, head_W, head_b, head_out);
    k_heads<<<1024, 256, 0, stream>>>(GS, dep_W, dep_b, dep_out);
}

// Round 3
// 819.426 us; speedup vs baseline: 5.6072x; 2.2108x over previous
//
#include <hip/hip_runtime.h>
#include <hip/hip_bf16.h>

#define HH 256
#define SS 128
#define BB 8
#define MM 128
#define DD 256
#define TT 256
#define GG 16   // rows per edge WG
#define NW 8    // waves per edge WG

typedef float  f32x4  __attribute__((ext_vector_type(4)));
typedef short  bf16x8 __attribute__((ext_vector_type(8)));

__device__ __forceinline__ unsigned short f2bf(float x) {
    unsigned u = __float_as_uint(x);
    return (unsigned short)((u + 0x7fffu + ((u >> 16) & 1u)) >> 16);
}
// fast tanh: 1 - 2/(e^{2x}+1); |err| ~1e-7, far below bf16 state rounding
__device__ __forceinline__ float ftanh(float x) {
    float e = __expf(2.0f * x);
    return 1.0f - 2.0f * __builtin_amdgcn_rcpf(e + 1.0f);
}

// ---------------- pack 256x256 W (row-major, out x in) into MFMA A-fragments ----------------
// frag f = ct*8 + kb; lane l holds W[ct*16 + (l&15)][kb*32 + (l>>4)*4 + (e&3) + 16*(e>>2)]
__global__ void k_pack(const float* __restrict__ W, unsigned short* __restrict__ pk) {
    int idx = blockIdx.x * 256 + threadIdx.x;   // 8192 = 128 frags * 64 lanes
    int f = idx >> 6, l = idx & 63;
    int ct = f >> 3, kb = f & 7, q = l >> 4, m = l & 15;
    unsigned short out[8];
#pragma unroll
    for (int e = 0; e < 8; e++) {
        int k = kb * 32 + q * 4 + (e & 3) + ((e >> 2) << 4);
        out[e] = f2bf(W[(ct * 16 + m) * HH + k]);
    }
    uint4 v;
    v.x = out[0] | ((unsigned)out[1] << 16);
    v.y = out[2] | ((unsigned)out[3] << 16);
    v.z = out[4] | ((unsigned)out[5] << 16);
    v.w = out[6] | ((unsigned)out[7] << 16);
    *(uint4*)(pk + idx * 8) = v;
}

// ---------------- transpose eW_ih0 (256 x 128) -> (128 x 256) f32 ----------------
__global__ void k_transp(const float* __restrict__ in, float* __restrict__ out) {
    int idx = blockIdx.x * 256 + threadIdx.x;   // 32768
    int j = idx >> 8, c = idx & 255;
    out[idx] = in[c * MM + j];
}

// ---------------- X0T[t][i/4][b][i%4] = input @ gW_ih0^T + gb_ih0 + gb_hh0 ----------------
__global__ void k_x0(const float* __restrict__ x, const float* __restrict__ Wih0,
                     const float* __restrict__ bih0, const float* __restrict__ bhh0,
                     float* __restrict__ X0T) {
    int row = blockIdx.x;           // b*SS + t
    int i = threadIdx.x;
    const float4* xr = (const float4*)(x + row * DD);
    const float4* wr = (const float4*)(Wih0 + i * DD);
    float a0 = 0.f, a1 = 0.f, a2 = 0.f, a3 = 0.f;
#pragma unroll 8
    for (int k = 0; k < DD / 4; k++) {
        float4 xv = xr[k]; float4 wv = wr[k];
        a0 += xv.x * wv.x; a1 += xv.y * wv.y; a2 += xv.z * wv.z; a3 += xv.w * wv.w;
    }
    float val = a0 + a1 + a2 + a3 + bih0[i] + bhh0[i];
    int b = row >> 7, t = row & (SS - 1);
    X0T[t * 2048 + (i >> 2) * 32 + b * 4 + (i & 3)] = val;
}

// ---------------- shared MFMA fragment loaders ----------------
__device__ __forceinline__ bf16x8 ldA(const unsigned short* __restrict__ pk, int ct, int kb, int lane) {
    return *(const bf16x8*)(pk + (((ct * 8 + kb) * 64 + lane) << 3));
}
__device__ __forceinline__ bf16x8 ldB(const unsigned short* h, int kb, int q) {
    const unsigned short* p = h + kb * 32 + q * 4;
    ushort4 lo = *(const ushort4*)p;
    ushort4 hi = *(const ushort4*)(p + 16);
    bf16x8 f;
    f[0] = lo.x; f[1] = lo.y; f[2] = lo.z; f[3] = lo.w;
    f[4] = hi.x; f[5] = hi.y; f[6] = hi.z; f[7] = hi.w;
    return f;
}

// ---------------- graph RNN, MFMA, weights-in-VGPR: ONE WG, 8 waves ----------------
// wave w owns output col-tiles {2w, 2w+1}; batch rows in B-operand slots 0..7 (8..15 = zero pad)
#define HST 264
__global__ __launch_bounds__(512, 2) void k_graph_mfma(
    const float* __restrict__ X0T, const int* __restrict__ mask,
    const unsigned short* __restrict__ pk0,  // gW_hh0 packed
    const unsigned short* __restrict__ pk1,  // gW_ih1 packed
    const unsigned short* __restrict__ pk2,  // gW_hh1 packed
    const float* __restrict__ bih1, const float* __restrict__ bhh1,
    float* __restrict__ GS) {
    __shared__ unsigned short h0[2][16][HST];
    __shared__ unsigned short h1[2][16][HST];
    __shared__ int lenS[16];

    int tid = threadIdx.x;
    int wv = tid >> 6, lane = tid & 63;
    int q = lane >> 4, rr = lane & 15;
    int ct0 = 2 * wv;
    int m0 = ct0 * 16 + q * 4;      // first owned out-col of ct0 tile

    // zero h buffers (both, both phases)
    {
        unsigned* p0 = (unsigned*)&h0[0][0][0];
        unsigned* p1 = (unsigned*)&h1[0][0][0];
        for (int idx = tid; idx < 2 * 16 * HST / 2; idx += 512) { p0[idx] = 0; p1[idx] = 0; }
    }
    // lengths: wave wv sums mask row wv
    {
        int s = mask[wv * SS + lane] + mask[wv * SS + 64 + lane];
        for (int off = 32; off; off >>= 1) s += __shfl_xor(s, off);
        if (lane == 0) lenS[wv] = s;
        if (tid < 8) lenS[8 + tid] = 0;
    }
    // weights -> VGPRs (192 regs/lane), bf16 fragment order
    bf16x8 a0[2][8], a1[2][8], a2[2][8];
#pragma unroll
    for (int kb = 0; kb < 8; kb++) {
        a0[0][kb] = ldA(pk0, ct0, kb, lane); a0[1][kb] = ldA(pk0, ct0 + 1, kb, lane);
        a1[0][kb] = ldA(pk1, ct0, kb, lane); a1[1][kb] = ldA(pk1, ct0 + 1, kb, lane);
        a2[0][kb] = ldA(pk2, ct0, kb, lane); a2[1][kb] = ldA(pk2, ct0 + 1, kb, lane);
    }
    f32x4 b1A, b1B;
    {
        int iA = ct0 * 4 + q;
        b1A = *(const f32x4*)(bih1 + iA * 4) + *(const f32x4*)(bhh1 + iA * 4);
        b1B = *(const f32x4*)(bih1 + (iA + 4) * 4) + *(const f32x4*)(bhh1 + (iA + 4) * 4);
    }
    __syncthreads();
    int lenr = lenS[rr];

    unsigned short* h0f = &h0[0][0][0];
    unsigned short* h1f = &h1[0][0][0];
    const int rowoff = rr * HST;
    const float* x0p = X0T + (ct0 * 4 + q) * 32 + rr * 4;
    float* gsp = GS + rr * (SS * HH) + m0;

    for (int t = 0; t < SS; t++) {
        int jr = t & 1, jw = jr ^ 1;
        bool v = t < lenr;
        const unsigned short* r0 = h0f + jr * (16 * HST) + rowoff;  // h0[jr] lane-row
        unsigned short* w0 = h0f + jw * (16 * HST) + rowoff;
        // ---- layer 0 ----
        f32x4 accA = {0.f, 0.f, 0.f, 0.f}, accB = {0.f, 0.f, 0.f, 0.f};
        if (rr < 8) { accA = *(const f32x4*)x0p; accB = *(const f32x4*)(x0p + 128); }
#pragma unroll
        for (int kb = 0; kb < 8; kb++) {
            bf16x8 b = ldB(r0, kb, q);
            accA = __builtin_amdgcn_mfma_f32_16x16x32_bf16(a0[0][kb], b, accA, 0, 0, 0);
            accB = __builtin_amdgcn_mfma_f32_16x16x32_bf16(a0[1][kb], b, accB, 0, 0, 0);
        }
        {
            unsigned nA0 = f2bf(ftanh(accA[0])) | ((unsigned)f2bf(ftanh(accA[1])) << 16);
            unsigned nA1 = f2bf(ftanh(accA[2])) | ((unsigned)f2bf(ftanh(accA[3])) << 16);
            unsigned nB0 = f2bf(ftanh(accB[0])) | ((unsigned)f2bf(ftanh(accB[1])) << 16);
            unsigned nB1 = f2bf(ftanh(accB[2])) | ((unsigned)f2bf(ftanh(accB[3])) << 16);
            uint2 oldA = *(const uint2*)(r0 + m0);
            uint2 oldB = *(const uint2*)(r0 + m0 + 16);
            uint2 outA = { v ? nA0 : oldA.x, v ? nA1 : oldA.y };
            uint2 outB = { v ? nB0 : oldB.x, v ? nB1 : oldB.y };
            *(uint2*)(w0 + m0) = outA;
            *(uint2*)(w0 + m0 + 16) = outB;
        }
        __syncthreads();   // B1: h0[jw] complete
        // ---- layer 1 ----
        const unsigned short* rn = h0f + jw * (16 * HST) + rowoff;  // new h0
        const unsigned short* r1 = h1f + jr * (16 * HST) + rowoff;  // old h1
        unsigned short* w1 = h1f + jw * (16 * HST) + rowoff;
        f32x4 pA = b1A, pB = b1B;
#pragma unroll
        for (int kb = 0; kb < 8; kb++) {
            bf16x8 be = ldB(rn, kb, q);
            bf16x8 bh = ldB(r1, kb, q);
            pA = __builtin_amdgcn_mfma_f32_16x16x32_bf16(a1[0][kb], be, pA, 0, 0, 0);
            pB = __builtin_amdgcn_mfma_f32_16x16x32_bf16(a1[1][kb], be, pB, 0, 0, 0);
            pA = __builtin_amdgcn_mfma_f32_16x16x32_bf16(a2[0][kb], bh, pA, 0, 0, 0);
            pB = __builtin_amdgcn_mfma_f32_16x16x32_bf16(a2[1][kb], bh, pB, 0, 0, 0);
        }
        float eA[4], eB[4];
#pragma unroll
        for (int r = 0; r < 4; r++) { eA[r] = ftanh(pA[r]); eB[r] = ftanh(pB[r]); }
        {
            unsigned nA0 = f2bf(eA[0]) | ((unsigned)f2bf(eA[1]) << 16);
            unsigned nA1 = f2bf(eA[2]) | ((unsigned)f2bf(eA[3]) << 16);
            unsigned nB0 = f2bf(eB[0]) | ((unsigned)f2bf(eB[1]) << 16);
            unsigned nB1 = f2bf(eB[2]) | ((unsigned)f2bf(eB[3]) << 16);
            uint2 oldA = *(const uint2*)(r1 + m0);
            uint2 oldB = *(const uint2*)(r1 + m0 + 16);
            uint2 outA = { v ? nA0 : oldA.x, v ? nA1 : oldA.y };
            uint2 outB = { v ? nB0 : oldB.x, v ? nB1 : oldB.y };
            *(uint2*)(w1 + m0) = outA;
            *(uint2*)(w1 + m0 + 16) = outB;
        }
        if (rr < 8) {
            f32x4 yA, yB;
#pragma unroll
            for (int r = 0; r < 4; r++) { yA[r] = v ? eA[r] : 0.f; yB[r] = v ? eB[r] : 0.f; }
            *(f32x4*)gsp = yA;
            *(f32x4*)(gsp + 16) = yB;
        }
        __syncthreads();   // B2: h1[jw] complete
        x0p += 2048;
        gsp += HH;
    }
}

// ---------------- edge RNN scan, MFMA (unchanged from R2) ----------------
__global__ __launch_bounds__(512) void k_edge_mfma(
    const float* __restrict__ GS,
    const unsigned short* __restrict__ pk0,  // eW_hh0 packed
    const unsigned short* __restrict__ pk1,  // eW_ih1 packed
    const unsigned short* __restrict__ pk2,  // eW_hh1 packed
    const float* __restrict__ eWT,           // eW_ih0^T (128 x 256) f32
    const float* __restrict__ bih0, const float* __restrict__ bhh0,
    const float* __restrict__ bih1, const float* __restrict__ bhh1,
    const float* __restrict__ clsW, const float* __restrict__ clsB,
    float* __restrict__ arc) {
    __shared__ unsigned short h0[2][GG][264];
    __shared__ unsigned short h1[2][GG][264];
    __shared__ float xw0[GG][260];
    __shared__ float red[NW][GG];
    __shared__ float edge_s[GG];

    int tid = threadIdx.x;
    int wv = tid >> 6, lane = tid & 63;
    int q = lane >> 4, rr = lane & 15;
    int ct0 = 2 * wv, ct1 = 2 * wv + 1;
    int r0 = blockIdx.x * GG;

    {
        int r = tid >> 5, c0 = (tid & 31) * 8;
        const float* g = GS + (r0 + r) * HH + c0;
        unsigned short t8[8];
#pragma unroll
        for (int e = 0; e < 8; e++) {
            float v = g[e];
            t8[e] = f2bf(v);
            xw0[r][c0 + e] = bih0[c0 + e] + bhh0[c0 + e];
        }
        uint4 pv;
        pv.x = t8[0] | ((unsigned)t8[1] << 16);
        pv.y = t8[2] | ((unsigned)t8[3] << 16);
        pv.z = t8[4] | ((unsigned)t8[5] << 16);
        pv.w = t8[6] | ((unsigned)t8[7] << 16);
        *(uint4*)&h0[0][r][c0] = pv;
        *(uint4*)&h1[0][r][c0] = pv;
    }
    float b1a[4], b1b[4], cwa[4], cwb[4];
#pragma unroll
    for (int reg = 0; reg < 4; reg++) {
        int cA = ct0 * 16 + q * 4 + reg;
        int cB = ct1 * 16 + q * 4 + reg;
        b1a[reg] = bih1[cA] + bhh1[cA];
        b1b[reg] = bih1[cB] + bhh1[cB];
        cwa[reg] = clsW[cA];
        cwb[reg] = clsW[cB];
    }
    float clsb = clsB[0];
    __syncthreads();

    for (int j = 0; j < MM; j++) {
        int jr = j & 1, jw = jr ^ 1;
        f32x4 acc0 = *(const f32x4*)&xw0[rr][ct0 * 16 + q * 4];
        f32x4 acc1 = *(const f32x4*)&xw0[rr][ct1 * 16 + q * 4];
#pragma unroll
        for (int kb = 0; kb < 8; kb++) {
            bf16x8 b = ldB(&h0[jr][rr][0], kb, q);
            acc0 = __builtin_amdgcn_mfma_f32_16x16x32_bf16(ldA(pk0, ct0, kb, lane), b, acc0, 0, 0, 0);
            acc1 = __builtin_amdgcn_mfma_f32_16x16x32_bf16(ldA(pk0, ct1, kb, lane), b, acc1, 0, 0, 0);
        }
        unsigned short e0a[4], e0b[4];
#pragma unroll
        for (int reg = 0; reg < 4; reg++) {
            e0a[reg] = f2bf(tanhf(acc0[reg]));
            e0b[reg] = f2bf(tanhf(acc1[reg]));
        }
        {
            ushort4 pa = { e0a[0], e0a[1], e0a[2], e0a[3] };
            ushort4 pb = { e0b[0], e0b[1], e0b[2], e0b[3] };
            *(ushort4*)&h0[jw][rr][ct0 * 16 + q * 4] = pa;
            *(ushort4*)&h0[jw][rr][ct1 * 16 + q * 4] = pb;
        }
        __syncthreads();
        f32x4 p0 = { b1a[0], b1a[1], b1a[2], b1a[3] };
        f32x4 p1 = { b1b[0], b1b[1], b1b[2], b1b[3] };
#pragma unroll
        for (int kb = 0; kb < 8; kb++) {
            bf16x8 be = ldB(&h0[jw][rr][0], kb, q);
            bf16x8 bh = ldB(&h1[jr][rr][0], kb, q);
            p0 = __builtin_amdgcn_mfma_f32_16x16x32_bf16(ldA(pk1, ct0, kb, lane), be, p0, 0, 0, 0);
            p1 = __builtin_amdgcn_mfma_f32_16x16x32_bf16(ldA(pk1, ct1, kb, lane), be, p1, 0, 0, 0);
            p0 = __builtin_amdgcn_mfma_f32_16x16x32_bf16(ldA(pk2, ct0, kb, lane), bh, p0, 0, 0, 0);
            p1 = __builtin_amdgcn_mfma_f32_16x16x32_bf16(ldA(pk2, ct1, kb, lane), bh, p1, 0, 0, 0);
        }
        float e1a[4], e1b[4];
        float part = 0.f;
#pragma unroll
        for (int reg = 0; reg < 4; reg++) {
            e1a[reg] = tanhf(p0[reg]);
            e1b[reg] = tanhf(p1[reg]);
            part += cwa[reg] * e1a[reg] + cwb[reg] * e1b[reg];
        }
        part += __shfl_xor(part, 16);
        part += __shfl_xor(part, 32);
        if (lane < 16) red[wv][lane] = part;
        __syncthreads();
        {
            ushort4 pa = { f2bf(e1a[0]), f2bf(e1a[1]), f2bf(e1a[2]), f2bf(e1a[3]) };
            ushort4 pb = { f2bf(e1b[0]), f2bf(e1b[1]), f2bf(e1b[2]), f2bf(e1b[3]) };
            *(ushort4*)&h1[jw][rr][ct0 * 16 + q * 4] = pa;
            *(ushort4*)&h1[jw][rr][ct1 * 16 + q * 4] = pb;
        }
        if (tid < GG) {
            float s = clsb;
#pragma unroll
            for (int w = 0; w < NW; w++) s += red[w][tid];
            edge_s[tid] = 1.f / (1.f + expf(-s));
        }
        __syncthreads();
        {
            int r = tid >> 5, c0 = (tid & 31) * 8;
            float e = edge_s[r];
            const float* wj = eWT + j * HH + c0;
#pragma unroll
            for (int k = 0; k < 8; k++) xw0[r][c0 + k] += e * wj[k];
        }
        if (tid < GG) {
            int row = r0 + tid;
            int b = row >> 7, s = row & 127;
            arc[b * (MM * SS) + j * SS + s] = (j < s) ? edge_s[tid] : 0.f;
        }
        __syncthreads();
    }
}

// ---------------- head/dep tags: elu(GS @ W^T + b) ----------------
__global__ void k_heads(const float* __restrict__ GS,
                        const float* __restrict__ W, const float* __restrict__ bias,
                        float* __restrict__ out) {
    int row = blockIdx.x;
    int i = threadIdx.x;
    const float4* gr = (const float4*)(GS + row * HH);
    const float4* wr = (const float4*)(W + i * HH);
    float a0 = 0.f, a1 = 0.f, a2 = 0.f, a3 = 0.f;
#pragma unroll 8
    for (int k = 0; k < HH / 4; k++) {
        float4 g = gr[k]; float4 w = wr[k];
        a0 += g.x * w.x; a1 += g.y * w.y; a2 += g.z * w.z; a3 += g.w * w.w;
    }
    float v = a0 + a1 + a2 + a3 + bias[i];
    out[row * TT + i] = (v > 0.f) ? v : expm1f(v);
}

extern "C" void kernel_launch(void* const* d_in, const int* in_sizes, int n_in,
                              void* d_out, int out_size, void* d_ws, size_t ws_size,
                              hipStream_t stream) {
    const float* input  = (const float*)d_in[0];
    const int*   mask   = (const int*)d_in[2];
    const float* gW_ih0 = (const float*)d_in[5];
    const float* gW_hh0 = (const float*)d_in[6];
    const float* gb_ih0 = (const float*)d_in[7];
    const float* gb_hh0 = (const float*)d_in[8];
    const float* gW_ih1 = (const float*)d_in[9];
    const float* gW_hh1 = (const float*)d_in[10];
    const float* gb_ih1 = (const float*)d_in[11];
    const float* gb_hh1 = (const float*)d_in[12];
    const float* eW_ih0 = (const float*)d_in[13];
    const float* eW_hh0 = (const float*)d_in[14];
    const float* eb_ih0 = (const float*)d_in[15];
    const float* eb_hh0 = (const float*)d_in[16];
    const float* eW_ih1 = (const float*)d_in[17];
    const float* eW_hh1 = (const float*)d_in[18];
    const float* eb_ih1 = (const float*)d_in[19];
    const float* eb_hh1 = (const float*)d_in[20];
    const float* cls_W  = (const float*)d_in[21];
    const float* cls_b  = (const float*)d_in[22];
    const float* head_W = (const float*)d_in[23];
    const float* head_b = (const float*)d_in[24];
    const float* dep_W  = (const float*)d_in[25];
    const float* dep_b  = (const float*)d_in[26];

    float* out      = (float*)d_out;
    float* head_out = out;                 // 8*128*256
    float* dep_out  = out + 262144;
    float* arc_out  = out + 524288;        // 8*128*128

    char* ws = (char*)d_ws;
    float* X0T = (float*)ws;                                  // 1 MB: [t][i/4][b8][4]
    float* GS  = (float*)(ws + (1 << 20));                    // 1 MB
    unsigned short* pk_g0 = (unsigned short*)(ws + (2 << 20)); // 128 KB each
    unsigned short* pk_g1 = pk_g0 + 65536;
    unsigned short* pk_g2 = pk_g0 + 2 * 65536;
    unsigned short* pk_e0 = pk_g0 + 3 * 65536;
    unsigned short* pk_e1 = pk_g0 + 4 * 65536;
    unsigned short* pk_e2 = pk_g0 + 5 * 65536;
    float* eWT = (float*)(pk_g0 + 6 * 65536);                 // 128 KB

    k_pack<<<32, 256, 0, stream>>>(gW_hh0, pk_g0);
    k_pack<<<32, 256, 0, stream>>>(gW_ih1, pk_g1);
    k_pack<<<32, 256, 0, stream>>>(gW_hh1, pk_g2);
    k_pack<<<32, 256, 0, stream>>>(eW_hh0, pk_e0);
    k_pack<<<32, 256, 0, stream>>>(eW_ih1, pk_e1);
    k_pack<<<32, 256, 0, stream>>>(eW_hh1, pk_e2);
    k_transp<<<128, 256, 0, stream>>>(eW_ih0, eWT);

    k_x0<<<1024, 256, 0, stream>>>(input, gW_ih0, gb_ih0, gb_hh0, X0T);
    k_graph_mfma<<<1, 512, 0, stream>>>(X0T, mask, pk_g0, pk_g1, pk_g2, gb_ih1, gb_hh1, GS);
    k_edge_mfma<<<64, 512, 0, stream>>>(GS, pk_e0, pk_e1, pk_e2, eWT,
                                        eb_ih0, eb_hh0, eb_ih1, eb_hh1, cls_W, cls_b, arc_out);
    k_heads<<<1024, 256, 0, stream>>>(GS, head_W, head_b, head_out);
    k_heads<<<1024, 256, 0, stream>>>(GS, dep_W, dep_b, dep_out);
}

// Round 4
// 569.111 us; speedup vs baseline: 8.0735x; 1.4398x over previous
//
#include <hip/hip_runtime.h>
#include <hip/hip_bf16.h>

#define HH 256
#define SS 128
#define BB 8
#define MM 128
#define DD 256
#define TT 256
#define GG 16   // rows per edge WG
#define NW 8    // waves per WG

// fragment-layout LDS: row stride 33 groups of 16B (odd -> minimal bank conflicts)
#define ROWG 33
#define FBUF (16 * ROWG * 8)   // ushorts per phase buffer (16 rows)

typedef float  f32x4  __attribute__((ext_vector_type(4)));
typedef short  bf16x8 __attribute__((ext_vector_type(8)));

__device__ __forceinline__ unsigned short f2bf(float x) {
    unsigned u = __float_as_uint(x);
    return (unsigned short)((u + 0x7fffu + ((u >> 16) & 1u)) >> 16);
}
__device__ __forceinline__ unsigned pk2bf(float a, float b) {
    return (unsigned)f2bf(a) | ((unsigned)f2bf(b) << 16);
}
// fast tanh: 1 - 2/(e^{2x}+1)
__device__ __forceinline__ float ftanh(float x) {
    float e = __expf(2.0f * x);
    return 1.0f - 2.0f * __builtin_amdgcn_rcpf(e + 1.0f);
}
__device__ __forceinline__ float fsigm(float x) {
    return __builtin_amdgcn_rcpf(1.0f + __expf(-x));
}

// ---------------- pack 256x256 W (row-major, out x in) into MFMA A-fragments ----------------
__global__ void k_pack(const float* __restrict__ W, unsigned short* __restrict__ pk) {
    int idx = blockIdx.x * 256 + threadIdx.x;   // 8192 = 128 frags * 64 lanes
    int f = idx >> 6, l = idx & 63;
    int ct = f >> 3, kb = f & 7, q = l >> 4, m = l & 15;
    unsigned short out[8];
#pragma unroll
    for (int e = 0; e < 8; e++) {
        int k = kb * 32 + q * 4 + (e & 3) + ((e >> 2) << 4);
        out[e] = f2bf(W[(ct * 16 + m) * HH + k]);
    }
    uint4 v;
    v.x = out[0] | ((unsigned)out[1] << 16);
    v.y = out[2] | ((unsigned)out[3] << 16);
    v.z = out[4] | ((unsigned)out[5] << 16);
    v.w = out[6] | ((unsigned)out[7] << 16);
    *(uint4*)(pk + idx * 8) = v;
}

// ---------------- transpose eW_ih0 (256 x 128) -> (128 x 256) f32 ----------------
__global__ void k_transp(const float* __restrict__ in, float* __restrict__ out) {
    int idx = blockIdx.x * 256 + threadIdx.x;   // 32768
    int j = idx >> 8, c = idx & 255;
    out[idx] = in[c * MM + j];
}

// ---------------- X0T[t][i/4][b][i%4] = input @ gW_ih0^T + gb_ih0 + gb_hh0 ----------------
__global__ void k_x0(const float* __restrict__ x, const float* __restrict__ Wih0,
                     const float* __restrict__ bih0, const float* __restrict__ bhh0,
                     float* __restrict__ X0T) {
    int row = blockIdx.x;           // b*SS + t
    int i = threadIdx.x;
    const float4* xr = (const float4*)(x + row * DD);
    const float4* wr = (const float4*)(Wih0 + i * DD);
    float a0 = 0.f, a1 = 0.f, a2 = 0.f, a3 = 0.f;
#pragma unroll 8
    for (int k = 0; k < DD / 4; k++) {
        float4 xv = xr[k]; float4 wv = wr[k];
        a0 += xv.x * wv.x; a1 += xv.y * wv.y; a2 += xv.z * wv.z; a3 += xv.w * wv.w;
    }
    float val = a0 + a1 + a2 + a3 + bih0[i] + bhh0[i];
    int b = row >> 7, t = row & (SS - 1);
    X0T[t * 2048 + (i >> 2) * 32 + b * 4 + (i & 3)] = val;
}

// ---------------- MFMA fragment loaders ----------------
__device__ __forceinline__ bf16x8 ldA(const unsigned short* __restrict__ pk, int ct, int kb, int lane) {
    return *(const bf16x8*)(pk + (((ct * 8 + kb) * 64 + lane) << 3));
}
// B-fragment from fragment-layout LDS buffer: group (row, kb, q)
__device__ __forceinline__ bf16x8 ldBf(const unsigned short* base, int row, int kb, int q) {
    return *(const bf16x8*)(base + ((row * ROWG + kb * 4 + q) << 3));
}

// ---------------- graph RNN, MFMA, weights-in-VGPR: ONE WG, 8 waves ----------------
__global__ __launch_bounds__(512, 2) void k_graph_mfma(
    const float* __restrict__ X0T, const int* __restrict__ mask,
    const unsigned short* __restrict__ pk0,  // gW_hh0 packed
    const unsigned short* __restrict__ pk1,  // gW_ih1 packed
    const unsigned short* __restrict__ pk2,  // gW_hh1 packed
    const float* __restrict__ bih1, const float* __restrict__ bhh1,
    float* __restrict__ GS) {
    __shared__ alignas(16) unsigned short h0[2 * FBUF];
    __shared__ alignas(16) unsigned short h1[2 * FBUF];
    __shared__ int lenS[16];

    int tid = threadIdx.x;
    int wv = tid >> 6, lane = tid & 63;
    int q = lane >> 4, rr = lane & 15;
    int ct0 = 2 * wv;
    int m0 = ct0 * 16 + q * 4;          // first owned out-col
    int goff = (rr * ROWG + wv * 4 + q) << 3;   // own write group (ushort units)

    // zero both phases of both buffers
    {
        uint4* p0 = (uint4*)h0;
        uint4* p1 = (uint4*)h1;
        for (int idx = tid; idx < 2 * FBUF / 8; idx += 512) { p0[idx] = uint4{0,0,0,0}; p1[idx] = uint4{0,0,0,0}; }
    }
    // lengths: wave wv sums mask row wv
    {
        int s = mask[wv * SS + lane] + mask[wv * SS + 64 + lane];
        for (int off = 32; off; off >>= 1) s += __shfl_xor(s, off);
        if (lane == 0) lenS[wv] = s;
        if (tid < 8) lenS[8 + tid] = 0;
    }
    // weights -> VGPRs (192 regs/lane)
    bf16x8 a0[2][8], a1[2][8], a2[2][8];
#pragma unroll
    for (int kb = 0; kb < 8; kb++) {
        a0[0][kb] = ldA(pk0, ct0, kb, lane); a0[1][kb] = ldA(pk0, ct0 + 1, kb, lane);
        a1[0][kb] = ldA(pk1, ct0, kb, lane); a1[1][kb] = ldA(pk1, ct0 + 1, kb, lane);
        a2[0][kb] = ldA(pk2, ct0, kb, lane); a2[1][kb] = ldA(pk2, ct0 + 1, kb, lane);
    }
    f32x4 b1A = *(const f32x4*)(bih1 + m0) + *(const f32x4*)(bhh1 + m0);
    f32x4 b1B = *(const f32x4*)(bih1 + m0 + 16) + *(const f32x4*)(bhh1 + m0 + 16);
    __syncthreads();
    int lenr = lenS[rr];

    const float* x0p = X0T + (8 * wv + q) * 32 + rr * 4;
    float* gsp = GS + rr * (SS * HH) + m0;

    for (int t = 0; t < SS; t++) {
        int jr = t & 1, jw = jr ^ 1;
        bool v = t < lenr;
        const unsigned short* r0 = h0 + jr * FBUF;
        // ---- layer 0 ----
        f32x4 accA = {0.f, 0.f, 0.f, 0.f}, accB = {0.f, 0.f, 0.f, 0.f};
        if (rr < 8) { accA = *(const f32x4*)x0p; accB = *(const f32x4*)(x0p + 128); }
#pragma unroll
        for (int kb = 0; kb < 8; kb++) {
            bf16x8 b = ldBf(r0, rr, kb, q);
            accA = __builtin_amdgcn_mfma_f32_16x16x32_bf16(a0[0][kb], b, accA, 0, 0, 0);
            accB = __builtin_amdgcn_mfma_f32_16x16x32_bf16(a0[1][kb], b, accB, 0, 0, 0);
        }
        {
            uint4 nv = { pk2bf(ftanh(accA[0]), ftanh(accA[1])), pk2bf(ftanh(accA[2]), ftanh(accA[3])),
                         pk2bf(ftanh(accB[0]), ftanh(accB[1])), pk2bf(ftanh(accB[2]), ftanh(accB[3])) };
            uint4 ov = *(const uint4*)(r0 + goff);
            uint4 sv = { v ? nv.x : ov.x, v ? nv.y : ov.y, v ? nv.z : ov.z, v ? nv.w : ov.w };
            *(uint4*)(h0 + jw * FBUF + goff) = sv;
        }
        __syncthreads();   // B1: h0[jw] complete
        // ---- layer 1 ----
        const unsigned short* rn = h0 + jw * FBUF;
        const unsigned short* r1 = h1 + jr * FBUF;
        f32x4 pA = b1A, pB = b1B;
#pragma unroll
        for (int kb = 0; kb < 8; kb++) {
            bf16x8 be = ldBf(rn, rr, kb, q);
            bf16x8 bh = ldBf(r1, rr, kb, q);
            pA = __builtin_amdgcn_mfma_f32_16x16x32_bf16(a1[0][kb], be, pA, 0, 0, 0);
            pB = __builtin_amdgcn_mfma_f32_16x16x32_bf16(a1[1][kb], be, pB, 0, 0, 0);
            pA = __builtin_amdgcn_mfma_f32_16x16x32_bf16(a2[0][kb], bh, pA, 0, 0, 0);
            pB = __builtin_amdgcn_mfma_f32_16x16x32_bf16(a2[1][kb], bh, pB, 0, 0, 0);
        }
        float eA[4], eB[4];
#pragma unroll
        for (int r = 0; r < 4; r++) { eA[r] = ftanh(pA[r]); eB[r] = ftanh(pB[r]); }
        {
            uint4 nv = { pk2bf(eA[0], eA[1]), pk2bf(eA[2], eA[3]),
                         pk2bf(eB[0], eB[1]), pk2bf(eB[2], eB[3]) };
            uint4 ov = *(const uint4*)(r1 + goff);
            uint4 sv = { v ? nv.x : ov.x, v ? nv.y : ov.y, v ? nv.z : ov.z, v ? nv.w : ov.w };
            *(uint4*)(h1 + jw * FBUF + goff) = sv;
        }
        if (rr < 8) {
            f32x4 yA, yB;
#pragma unroll
            for (int r = 0; r < 4; r++) { yA[r] = v ? eA[r] : 0.f; yB[r] = v ? eB[r] : 0.f; }
            *(f32x4*)gsp = yA;
            *(f32x4*)(gsp + 16) = yB;
        }
        __syncthreads();   // B2: h1[jw] complete
        x0p += 2048;
        gsp += HH;
    }
}

// ---------------- edge RNN scan: MFMA, weights-in-VGPR, xw0-in-registers ----------------
__global__ __launch_bounds__(512, 2) void k_edge_mfma(
    const float* __restrict__ GS,
    const unsigned short* __restrict__ pk0,  // eW_hh0 packed
    const unsigned short* __restrict__ pk1,  // eW_ih1 packed
    const unsigned short* __restrict__ pk2,  // eW_hh1 packed
    const float* __restrict__ eWT,           // eW_ih0^T (128 x 256) f32
    const float* __restrict__ bih0, const float* __restrict__ bhh0,
    const float* __restrict__ bih1, const float* __restrict__ bhh1,
    const float* __restrict__ clsW, const float* __restrict__ clsB,
    float* __restrict__ arc) {
    __shared__ alignas(16) unsigned short h0[2 * FBUF];
    __shared__ alignas(16) unsigned short h1[2 * FBUF];
    __shared__ float red[NW][GG];
    __shared__ float cws[HH];
    __shared__ float b1s[HH];

    int tid = threadIdx.x;
    int wv = tid >> 6, lane = tid & 63;
    int q = lane >> 4, rr = lane & 15;
    int m0 = 32 * wv + 4 * q;
    int goff = (rr * ROWG + wv * 4 + q) << 3;
    int r0 = blockIdx.x * GG;

    // init h0[0] = h1[0] = bf16(GS rows), fragment layout: thread = (row, group)
    {
        int r = tid >> 5, g = tid & 31;           // g = kb*4 + q
        int kb = g >> 2, qq = g & 3;
        int lo = kb * 32 + qq * 4;
        const float* gp = GS + (r0 + r) * HH + lo;
        float4 vlo = *(const float4*)gp;
        float4 vhi = *(const float4*)(gp + 16);
        uint4 pv = { pk2bf(vlo.x, vlo.y), pk2bf(vlo.z, vlo.w),
                     pk2bf(vhi.x, vhi.y), pk2bf(vhi.z, vhi.w) };
        int off = (r * ROWG + g) << 3;
        *(uint4*)(h0 + off) = pv;
        *(uint4*)(h1 + off) = pv;
    }
    if (tid < HH) {
        cws[tid] = clsW[tid];
        b1s[tid] = bih1[tid] + bhh1[tid];
    }
    // weights -> VGPRs
    bf16x8 a0[2][8], a1[2][8], a2[2][8];
#pragma unroll
    for (int kb = 0; kb < 8; kb++) {
        a0[0][kb] = ldA(pk0, 2 * wv, kb, lane); a0[1][kb] = ldA(pk0, 2 * wv + 1, kb, lane);
        a1[0][kb] = ldA(pk1, 2 * wv, kb, lane); a1[1][kb] = ldA(pk1, 2 * wv + 1, kb, lane);
        a2[0][kb] = ldA(pk2, 2 * wv, kb, lane); a2[1][kb] = ldA(pk2, 2 * wv + 1, kb, lane);
    }
    // xw0 in registers (D-layout)
    f32x4 xw0A = *(const f32x4*)(bih0 + m0) + *(const f32x4*)(bhh0 + m0);
    f32x4 xw0B = *(const f32x4*)(bih0 + m0 + 16) + *(const f32x4*)(bhh0 + m0 + 16);
    float clsb = clsB[0];
    int srow = (r0 + rr) & 127;      // sentence position of this lane's row
    int bidx = (r0 + rr) >> 7;
    __syncthreads();

    for (int j = 0; j < MM; j++) {
        int jr = j & 1, jw = jr ^ 1;
        // prefetch eW_ih0 column j slice (used after B2)
        f32x4 ewA = *(const f32x4*)(eWT + j * HH + m0);
        f32x4 ewB = *(const f32x4*)(eWT + j * HH + m0 + 16);
        // ---- layer 0: pre0 = xw0 + h0 @ Whh0^T ----
        const unsigned short* rb0 = h0 + jr * FBUF;
        f32x4 acc0 = xw0A, acc1 = xw0B;
#pragma unroll
        for (int kb = 0; kb < 8; kb++) {
            bf16x8 b = ldBf(rb0, rr, kb, q);
            acc0 = __builtin_amdgcn_mfma_f32_16x16x32_bf16(a0[0][kb], b, acc0, 0, 0, 0);
            acc1 = __builtin_amdgcn_mfma_f32_16x16x32_bf16(a0[1][kb], b, acc1, 0, 0, 0);
        }
        {
            uint4 nv = { pk2bf(ftanh(acc0[0]), ftanh(acc0[1])), pk2bf(ftanh(acc0[2]), ftanh(acc0[3])),
                         pk2bf(ftanh(acc1[0]), ftanh(acc1[1])), pk2bf(ftanh(acc1[2]), ftanh(acc1[3])) };
            *(uint4*)(h0 + jw * FBUF + goff) = nv;
        }
        __syncthreads();   // B1: h0[jw] complete
        // ---- layer 1 ----
        const unsigned short* rn = h0 + jw * FBUF;
        const unsigned short* r1 = h1 + jr * FBUF;
        f32x4 p0 = *(const f32x4*)&b1s[m0];
        f32x4 p1 = *(const f32x4*)&b1s[m0 + 16];
#pragma unroll
        for (int kb = 0; kb < 8; kb++) {
            bf16x8 be = ldBf(rn, rr, kb, q);
            bf16x8 bh = ldBf(r1, rr, kb, q);
            p0 = __builtin_amdgcn_mfma_f32_16x16x32_bf16(a1[0][kb], be, p0, 0, 0, 0);
            p1 = __builtin_amdgcn_mfma_f32_16x16x32_bf16(a1[1][kb], be, p1, 0, 0, 0);
            p0 = __builtin_amdgcn_mfma_f32_16x16x32_bf16(a2[0][kb], bh, p0, 0, 0, 0);
            p1 = __builtin_amdgcn_mfma_f32_16x16x32_bf16(a2[1][kb], bh, p1, 0, 0, 0);
        }
        float e1a[4], e1b[4];
#pragma unroll
        for (int r = 0; r < 4; r++) { e1a[r] = ftanh(p0[r]); e1b[r] = ftanh(p1[r]); }
        {
            uint4 nv = { pk2bf(e1a[0], e1a[1]), pk2bf(e1a[2], e1a[3]),
                         pk2bf(e1b[0], e1b[1]), pk2bf(e1b[2], e1b[3]) };
            *(uint4*)(h1 + jw * FBUF + goff) = nv;
        }
        // cls partial: dot with clsW over owned 8 cols, reduce over q
        f32x4 cwA = *(const f32x4*)&cws[m0];
        f32x4 cwB = *(const f32x4*)&cws[m0 + 16];
        float part = cwA[0] * e1a[0] + cwA[1] * e1a[1] + cwA[2] * e1a[2] + cwA[3] * e1a[3]
                   + cwB[0] * e1b[0] + cwB[1] * e1b[1] + cwB[2] * e1b[2] + cwB[3] * e1b[3];
        part += __shfl_xor(part, 16);
        part += __shfl_xor(part, 32);
        if (lane < 16) red[wv][lane] = part;
        __syncthreads();   // B2: red + h1[jw] complete
        // ---- all lanes: own-row sigmoid; rank-1 xw0 update in registers ----
        float s = clsb;
#pragma unroll
        for (int w = 0; w < NW; w++) s += red[w][rr];
        float edge = fsigm(s);
        xw0A += edge * ewA;
        xw0B += edge * ewB;
        if (tid < GG) {
            arc[bidx * (MM * SS) + j * SS + srow] = (j < srow) ? edge : 0.f;
        }
        // no barrier: red is re-written only after next B1
    }
}

// ---------------- head/dep tags: elu(GS @ W^T + b) ----------------
__global__ void k_heads(const float* __restrict__ GS,
                        const float* __restrict__ W, const float* __restrict__ bias,
                        float* __restrict__ out) {
    int row = blockIdx.x;
    int i = threadIdx.x;
    const float4* gr = (const float4*)(GS + row * HH);
    const float4* wr = (const float4*)(W + i * HH);
    float a0 = 0.f, a1 = 0.f, a2 = 0.f, a3 = 0.f;
#pragma unroll 8
    for (int k = 0; k < HH / 4; k++) {
        float4 g = gr[k]; float4 w = wr[k];
        a0 += g.x * w.x; a1 += g.y * w.y; a2 += g.z * w.z; a3 += g.w * w.w;
    }
    float v = a0 + a1 + a2 + a3 + bias[i];
    out[row * TT + i] = (v > 0.f) ? v : expm1f(v);
}

extern "C" void kernel_launch(void* const* d_in, const int* in_sizes, int n_in,
                              void* d_out, int out_size, void* d_ws, size_t ws_size,
                              hipStream_t stream) {
    const float* input  = (const float*)d_in[0];
    const int*   mask   = (const int*)d_in[2];
    const float* gW_ih0 = (const float*)d_in[5];
    const float* gW_hh0 = (const float*)d_in[6];
    const float* gb_ih0 = (const float*)d_in[7];
    const float* gb_hh0 = (const float*)d_in[8];
    const float* gW_ih1 = (const float*)d_in[9];
    const float* gW_hh1 = (const float*)d_in[10];
    const float* gb_ih1 = (const float*)d_in[11];
    const float* gb_hh1 = (const float*)d_in[12];
    const float* eW_ih0 = (const float*)d_in[13];
    const float* eW_hh0 = (const float*)d_in[14];
    const float* eb_ih0 = (const float*)d_in[15];
    const float* eb_hh0 = (const float*)d_in[16];
    const float* eW_ih1 = (const float*)d_in[17];
    const float* eW_hh1 = (const float*)d_in[18];
    const float* eb_ih1 = (const float*)d_in[19];
    const float* eb_hh1 = (const float*)d_in[20];
    const float* cls_W  = (const float*)d_in[21];
    const float* cls_b  = (const float*)d_in[22];
    const float* head_W = (const float*)d_in[23];
    const float* head_b = (const float*)d_in[24];
    const float* dep_W  = (const float*)d_in[25];
    const float* dep_b  = (const float*)d_in[26];

    float* out      = (float*)d_out;
    float* head_out = out;                 // 8*128*256
    float* dep_out  = out + 262144;
    float* arc_out  = out + 524288;        // 8*128*128

    char* ws = (char*)d_ws;
    float* X0T = (float*)ws;                                  // 1 MB: [t][i/4][b8][4]
    float* GS  = (float*)(ws + (1 << 20));                    // 1 MB
    unsigned short* pk_g0 = (unsigned short*)(ws + (2 << 20)); // 128 KB each
    unsigned short* pk_g1 = pk_g0 + 65536;
    unsigned short* pk_g2 = pk_g0 + 2 * 65536;
    unsigned short* pk_e0 = pk_g0 + 3 * 65536;
    unsigned short* pk_e1 = pk_g0 + 4 * 65536;
    unsigned short* pk_e2 = pk_g0 + 5 * 65536;
    float* eWT = (float*)(pk_g0 + 6 * 65536);                 // 128 KB

    k_pack<<<32, 256, 0, stream>>>(gW_hh0, pk_g0);
    k_pack<<<32, 256, 0, stream>>>(gW_ih1, pk_g1);
    k_pack<<<32, 256, 0, stream>>>(gW_hh1, pk_g2);
    k_pack<<<32, 256, 0, stream>>>(eW_hh0, pk_e0);
    k_pack<<<32, 256, 0, stream>>>(eW_ih1, pk_e1);
    k_pack<<<32, 256, 0, stream>>>(eW_hh1, pk_e2);
    k_transp<<<128, 256, 0, stream>>>(eW_ih0, eWT);

    k_x0<<<1024, 256, 0, stream>>>(input, gW_ih0, gb_ih0, gb_hh0, X0T);
    k_graph_mfma<<<1, 512, 0, stream>>>(X0T, mask, pk_g0, pk_g1, pk_g2, gb_ih1, gb_hh1, GS);
    k_edge_mfma<<<64, 512, 0, stream>>>(GS, pk_e0, pk_e1, pk_e2, eWT,
                                        eb_ih0, eb_hh0, eb_ih1, eb_hh1, cls_W, cls_b, arc_out);
    k_heads<<<1024, 256, 0, stream>>>(GS, head_W, head_b, head_out);
    k_heads<<<1024, 256, 0, stream>>>(GS, dep_W, dep_b, dep_out);
}